// Round 12
// baseline (1606.230 us; speedup 1.0000x reference)
//
#include <hip/hip_runtime.h>

// RGCN on MI355X. CSR-by-dst built once, then per conv:
//   Phase A: S[n, b*100+d] = sum_{e: dst=n} att[type_e,b]*norm_e*invdeg_n * x[src_e,d]  (fp32)
//   Phase B: out = [S | x] @ [basis_flat ; root] + bias  via MFMA bf16 with exact
//            3-way split (h+m+l, 6 products) == fp32-class accuracy.
// R11 (on R10's measured 1573us): (1) phaseA batch-4 edge pipeline (latency-bound
// serial loads were ~8% of FMA floor); (2) phaseB truncation-split (AND/SUB+pack,
// ~2x fewer VALU ops than int-RNE; VALUBusy 20% ~= MFMA time) + load-order fix.
// (R12 = identical resubmit of R11; R11 bench never ran: GPU acquisition timeout.)

#define DIMD 100
#define NBASES 10
#define KTOT 1100          // 1000 (S@basis) + 100 (x@root)
#define KC 32              // k per chunk
#define NCHUNK 35          // 35*32 = 1120 >= 1100
#define KPAD 1120
#define BTPLANE (128 * KPAD)          // shorts per split level
#define BTSIZE (3 * BTPLANE)          // shorts per param set (860,160 B)

typedef __attribute__((ext_vector_type(8))) short short8;   // 8 bf16 = 4 VGPR
typedef __attribute__((ext_vector_type(4))) float floatx4;  // MFMA acc

static inline size_t align256(size_t x) { return (x + 255) & ~(size_t)255; }

__device__ inline unsigned short f2bf_rne(float f) {
    unsigned u = __float_as_uint(f);
    unsigned r = u + 0x7FFFu + ((u >> 16) & 1u);
    return (unsigned short)(r >> 16);
}
__device__ inline float bf2f(unsigned short h) {
    return __uint_as_float(((unsigned)h) << 16);
}

// ---------------- preprocessing kernels ----------------

__global__ __launch_bounds__(256) void hist_kernel(const int* __restrict__ dst,
                                                   int* __restrict__ counts, int E) {
    int e = blockIdx.x * 256 + threadIdx.x;
    if (e < E) atomicAdd(&counts[dst[e]], 1);
}

__global__ __launch_bounds__(1024) void scan_kernel(const int* __restrict__ counts,
                                                    int* __restrict__ row_ptr,
                                                    int* __restrict__ next_pos, int n) {
    __shared__ int part[1024];
    __shared__ int base_s[1024];
    int t = threadIdx.x;
    int chunk = (n + 1023) / 1024;
    int lo = t * chunk, hi = min(lo + chunk, n);
    int s = 0;
    for (int i = lo; i < hi; ++i) s += counts[i];
    part[t] = s;
    __syncthreads();
    if (t == 0) {
        int run = 0;
        for (int i = 0; i < 1024; ++i) { int v = part[i]; base_s[i] = run; run += v; }
        row_ptr[n] = run;   // == E
    }
    __syncthreads();
    int run = base_s[t];
    for (int i = lo; i < hi; ++i) {
        row_ptr[i] = run;
        next_pos[i] = run;
        run += counts[i];
    }
}

__global__ __launch_bounds__(256) void scatter_kernel(
        const int* __restrict__ src, const int* __restrict__ dst,
        const int* __restrict__ etype, const float* __restrict__ enorm,
        const int* __restrict__ counts, int* __restrict__ next_pos,
        int* __restrict__ ssrc, int* __restrict__ stype, float* __restrict__ snid, int E) {
    int e = blockIdx.x * 256 + threadIdx.x;
    if (e < E) {
        int d = dst[e];
        int pos = atomicAdd(&next_pos[d], 1);
        ssrc[pos] = src[e];
        stype[pos] = etype[e];
        float deg = (float)max(counts[d], 1);
        snid[pos] = enorm[e] / deg;   // fold mean into per-edge coef
    }
}

__global__ __launch_bounds__(256) void gather_kernel(const int* __restrict__ entity,
                                                     const float* __restrict__ emb,
                                                     float* __restrict__ x, int total) {
    int i = blockIdx.x * 256 + threadIdx.x;
    if (i < total) {
        int n = i / DIMD;
        int d = i - n * DIMD;
        x[i] = emb[(size_t)entity[n] * DIMD + d];
    }
}

// ---- B pre-transpose + 3-way bf16 split: Bt[lv][col][k], col<128, k<1120 ----
__global__ __launch_bounds__(256) void transposeB_kernel(
        const float* __restrict__ Bm,   // [1000][100] basis flat
        const float* __restrict__ root, // [100][100]
        unsigned short* __restrict__ Bt) {
    int col = blockIdx.x;               // 0..127
    for (int k = threadIdx.x; k < KPAD; k += 256) {
        float v = 0.f;
        if (col < DIMD && k < KTOT)
            v = (k < 1000) ? Bm[(size_t)k * DIMD + col]
                           : root[(size_t)(k - 1000) * DIMD + col];
        unsigned short h = f2bf_rne(v);  float r  = v - bf2f(h);
        unsigned short m = f2bf_rne(r);  float r2 = r - bf2f(m);
        unsigned short l = f2bf_rne(r2);
        size_t o = (size_t)col * KPAD + k;
        Bt[o] = h;
        Bt[BTPLANE + o] = m;
        Bt[2 * BTPLANE + o] = l;
    }
}

// ---------------- Phase A: scatter into S (one wave per node) ----------------
// R11: batch-4 edge pipeline -- 4 independent {meta -> x-row} load chains in
// flight per iteration instead of 1 (was serial-latency-bound at ~600cyc/edge).

__global__ __launch_bounds__(256) void phaseA_kernel(
        const float* __restrict__ x, const int* __restrict__ row_ptr,
        const int* __restrict__ ssrc, const int* __restrict__ stype,
        const float* __restrict__ snid, const float* __restrict__ att,
        float* __restrict__ S, int N) {
    __shared__ float att_s[1000];   // [R=100][B=10]
    for (int i = threadIdx.x; i < 1000; i += 256) att_s[i] = att[i];
    __syncthreads();

    int wave = threadIdx.x >> 6;
    int l = threadIdx.x & 63;
    int n = blockIdx.x * 4 + wave;
    if (n >= N) return;

    int e0 = row_ptr[n], e1 = row_ptr[n + 1];
    float acc0[NBASES];
    float acc1[NBASES];
#pragma unroll
    for (int b = 0; b < NBASES; ++b) { acc0[b] = 0.f; acc1[b] = 0.f; }
    bool hi = (l < DIMD - 64);   // lanes 0..35 also own d = 64+l

    for (int e = e0; e < e1; e += 4) {
        float xa[4], xb[4], nv[4];
        int tt[4];
#pragma unroll
        for (int j = 0; j < 4; ++j) {          // 4 independent load chains
            if (e + j < e1) {
                int s = ssrc[e + j];
                tt[j] = stype[e + j];
                nv[j] = snid[e + j];
                const float* xr = x + (size_t)s * DIMD;
                xa[j] = xr[l];
                xb[j] = hi ? xr[64 + l] : 0.f;
            } else { tt[j] = 0; nv[j] = 0.f; xa[j] = 0.f; xb[j] = 0.f; }
        }
#pragma unroll
        for (int j = 0; j < 4; ++j) {          // same per-edge accum order as R10
            const float* ar = att_s + tt[j] * NBASES;
#pragma unroll
            for (int b = 0; b < NBASES; ++b) {
                float c = ar[b] * nv[j];
                acc0[b] += c * xa[j];
                acc1[b] += c * xb[j];
            }
        }
    }
    float* Sr = S + (size_t)n * (NBASES * DIMD);
#pragma unroll
    for (int b = 0; b < NBASES; ++b) {
        Sr[b * DIMD + l] = acc0[b];
        if (hi) Sr[b * DIMD + 64 + l] = acc1[b];
    }
}

// ---------------- Phase B: MFMA split-bf16 GEMM ----------------
// Tile 64 rows x 128 cols, 4 waves (wave w = cols w*32..w*32+31), KC=32.
// A split per chunk via TRUNCATION (AND/SUB, exact residuals; dropped terms
// ~2^-21 rel with the 6 retained products -- fp32-class). Staging order:
// A globals -> B globals -> convert A (waits A only) -> write A -> write B.

__global__ __launch_bounds__(256, 3) void phaseB_kernel(
        const float* __restrict__ S, const float* __restrict__ x,
        const unsigned short* __restrict__ Bt,   // [3][128][1120] bf16 pre-split
        const float* __restrict__ bias, float* __restrict__ out,
        int N, int do_relu) {
    __shared__ short Ah[64][40], Am[64][40], Al[64][40];     //  5120 B each
    __shared__ short Bh[128][40], Bmm[128][40], Bl[128][40]; // 10240 B each

    int tid = threadIdx.x;
    int w = tid >> 6, l = tid & 63;
    int lr = l & 15, kg8 = (l >> 4) * 8;
    int n0 = blockIdx.x * 64;

    // staging coords: A: thread -> (row, k-group of 8); B: idx -> (col, k-quad)
    int arow = tid >> 2, akq = tid & 3;
    int gr = min(n0 + arow, N - 1);
    const float* Sr = S + (size_t)gr * 1000;
    const float* xr = x + (size_t)gr * DIMD;

    floatx4 acc[4][2];
#pragma unroll
    for (int rf = 0; rf < 4; ++rf)
#pragma unroll
        for (int cf = 0; cf < 2; ++cf) acc[rf][cf] = (floatx4)(0.f);

    for (int c = 0; c < NCHUNK; ++c) {
        int k0 = c * KC;
        __syncthreads();   // previous chunk's readers done

        // ---- issue A global loads ----
        int kgb = k0 + akq * 8;
        float4 va = make_float4(0.f, 0.f, 0.f, 0.f), vb = va;
        if (kgb < 1000)      va = *(const float4*)(Sr + kgb);
        else if (kgb < KTOT) va = *(const float4*)(xr + (kgb - 1000));
        int kgb2 = kgb + 4;
        if (kgb2 < 1000)      vb = *(const float4*)(Sr + kgb2);
        else if (kgb2 < KTOT) vb = *(const float4*)(xr + (kgb2 - 1000));

        // ---- issue B global loads (pre-split bf16, 6x b128) ----
        short8 vB[6];
#pragma unroll
        for (int lv = 0; lv < 3; ++lv) {
            const unsigned short* plane = Bt + (size_t)lv * BTPLANE;
#pragma unroll
            for (int i = 0; i < 2; ++i) {
                int idx = tid + i * 256;            // 0..511
                int col = idx >> 2, kq = idx & 3;
                vB[lv * 2 + i] = *(const short8*)(plane + (size_t)col * KPAD + k0 + kq * 8);
            }
        }

        // ---- convert A: truncation split (waits only on A loads) ----
        {
            float v[8] = {va.x, va.y, va.z, va.w, vb.x, vb.y, vb.z, vb.w};
            unsigned hU[4], mU[4], lU[4];
#pragma unroll
            for (int i = 0; i < 4; ++i) {
                float a = v[2 * i], b = v[2 * i + 1];
                unsigned ua = __float_as_uint(a), ub = __float_as_uint(b);
                float ha = __uint_as_float(ua & 0xFFFF0000u);
                float hb = __uint_as_float(ub & 0xFFFF0000u);
                hU[i] = (ua >> 16) | (ub & 0xFFFF0000u);
                float ra = a - ha, rb = b - hb;          // exact
                unsigned ura = __float_as_uint(ra), urb = __float_as_uint(rb);
                float ma = __uint_as_float(ura & 0xFFFF0000u);
                float mb = __uint_as_float(urb & 0xFFFF0000u);
                mU[i] = (ura >> 16) | (urb & 0xFFFF0000u);
                float r2a = ra - ma, r2b = rb - mb;      // exact
                unsigned u2a = __float_as_uint(r2a), u2b = __float_as_uint(r2b);
                lU[i] = (u2a >> 16) | (u2b & 0xFFFF0000u);
            }
            *(uint4*)&Ah[arow][akq * 8] = make_uint4(hU[0], hU[1], hU[2], hU[3]);
            *(uint4*)&Am[arow][akq * 8] = make_uint4(mU[0], mU[1], mU[2], mU[3]);
            *(uint4*)&Al[arow][akq * 8] = make_uint4(lU[0], lU[1], lU[2], lU[3]);
        }
        // ---- write B planes ----
#pragma unroll
        for (int lv = 0; lv < 3; ++lv) {
#pragma unroll
            for (int i = 0; i < 2; ++i) {
                int idx = tid + i * 256;
                int col = idx >> 2, kq = idx & 3;
                short* dstL = (lv == 0) ? &Bh[col][kq * 8]
                             : (lv == 1) ? &Bmm[col][kq * 8] : &Bl[col][kq * 8];
                *(short8*)dstL = vB[lv * 2 + i];
            }
        }
        __syncthreads();

        // ---- B frags for this wave's 2 col-frags ----
        short8 bh[2], bm[2], bl[2];
#pragma unroll
        for (int cf = 0; cf < 2; ++cf) {
            int bc = w * 32 + cf * 16 + lr;
            bh[cf] = *(const short8*)&Bh[bc][kg8];
            bm[cf] = *(const short8*)&Bmm[bc][kg8];
            bl[cf] = *(const short8*)&Bl[bc][kg8];
        }
        // ---- 4 row-frags x 2 col-frags x 6 products ----
#pragma unroll
        for (int rf = 0; rf < 4; ++rf) {
            int ar = rf * 16 + lr;
            short8 ah = *(const short8*)&Ah[ar][kg8];
            short8 am = *(const short8*)&Am[ar][kg8];
            short8 al = *(const short8*)&Al[ar][kg8];
#pragma unroll
            for (int cf = 0; cf < 2; ++cf) {
                floatx4 a = acc[rf][cf];
                a = __builtin_amdgcn_mfma_f32_16x16x32_bf16(ah, bh[cf], a, 0, 0, 0);
                a = __builtin_amdgcn_mfma_f32_16x16x32_bf16(ah, bm[cf], a, 0, 0, 0);
                a = __builtin_amdgcn_mfma_f32_16x16x32_bf16(am, bh[cf], a, 0, 0, 0);
                a = __builtin_amdgcn_mfma_f32_16x16x32_bf16(ah, bl[cf], a, 0, 0, 0);
                a = __builtin_amdgcn_mfma_f32_16x16x32_bf16(al, bh[cf], a, 0, 0, 0);
                a = __builtin_amdgcn_mfma_f32_16x16x32_bf16(am, bm[cf], a, 0, 0, 0);
                acc[rf][cf] = a;
            }
        }
    }

    // ---- epilogue: C/D layout col=lane&15, row=(lane>>4)*4+j (m89-verified) ----
#pragma unroll
    for (int rf = 0; rf < 4; ++rf) {
#pragma unroll
        for (int cf = 0; cf < 2; ++cf) {
            int cidx = w * 32 + cf * 16 + lr;
            if (cidx < DIMD) {
                float bs = bias[cidx];
#pragma unroll
                for (int j = 0; j < 4; ++j) {
                    int r = n0 + rf * 16 + (l >> 4) * 4 + j;
                    if (r < N) {
                        float v = acc[rf][cf][j] + bs;
                        if (do_relu) v = fmaxf(v, 0.f);
                        out[(size_t)r * DIMD + cidx] = v;
                    }
                }
            }
        }
    }
}

// ---------------- driver ----------------

extern "C" void kernel_launch(void* const* d_in, const int* in_sizes, int n_in,
                              void* d_out, int out_size, void* d_ws, size_t ws_size,
                              hipStream_t stream) {
    const int* entity = (const int*)d_in[0];
    const int* edge_index = (const int*)d_in[1];
    const int* edge_type = (const int*)d_in[2];
    const float* edge_norm = (const float*)d_in[3];
    const float* emb = (const float*)d_in[4];
    const float* basisP[3] = {(const float*)d_in[5], (const float*)d_in[9], (const float*)d_in[13]};
    const float* attP[3]   = {(const float*)d_in[6], (const float*)d_in[10], (const float*)d_in[14]};
    const float* rootP[3]  = {(const float*)d_in[7], (const float*)d_in[11], (const float*)d_in[15]};
    const float* biasP[3]  = {(const float*)d_in[8], (const float*)d_in[12], (const float*)d_in[16]};

    const int N = in_sizes[0];
    const int E = in_sizes[1] / 2;
    const int* src = edge_index;
    const int* dst = edge_index + E;

    // workspace layout: R4's proven 250.2 MB footprint (unchanged)
    char* w = (char*)d_ws;
    float* S = (float*)w;            w += align256((size_t)N * NBASES * DIMD * 4);
    float* X0 = (float*)w;           w += align256((size_t)N * DIMD * 4);
    float* X1 = (float*)w;           w += align256((size_t)N * DIMD * 4);
    int* counts = (int*)w;           w += align256((size_t)N * 4);
    int* row_ptr = (int*)w;          w += align256((size_t)(N + 1) * 4);
    int* next_pos = (int*)w;         w += align256((size_t)N * 4);
    int* ssrc = (int*)w;             w += align256((size_t)E * 4);
    int* stype = (int*)w;            w += align256((size_t)E * 4);
    float* snid = (float*)w;         w += align256((size_t)E * 4);

    // Bt scratch: sets 0/1 live in d_out (scratch until l=4 writes it);
    // set 2 lives in X1 (dead after l=3 consumes it).
    unsigned short* Bt0 = (unsigned short*)d_out;
    unsigned short* Bt1 = Bt0 + BTSIZE;
    unsigned short* Bt2 = (unsigned short*)X1;

    // ---- build CSR by dst (shared by all 5 convs) ----
    hipMemsetAsync(counts, 0, (size_t)N * 4, stream);
    int gE = (E + 255) / 256;
    hist_kernel<<<gE, 256, 0, stream>>>(dst, counts, E);
    scan_kernel<<<1, 1024, 0, stream>>>(counts, row_ptr, next_pos, N);
    scatter_kernel<<<gE, 256, 0, stream>>>(src, dst, edge_type, edge_norm, counts,
                                           next_pos, ssrc, stype, snid, E);
    // ---- x0 = emb[entity] ----
    int totalX = N * DIMD;
    gather_kernel<<<(totalX + 255) / 256, 256, 0, stream>>>(entity, emb, X0, totalX);

    // ---- pre-split B for param sets 0 and 1 ----
    transposeB_kernel<<<128, 256, 0, stream>>>(basisP[0], rootP[0], Bt0);
    transposeB_kernel<<<128, 256, 0, stream>>>(basisP[1], rootP[1], Bt1);

    // ---- 5 conv layers: rotation bufin={X0,X1,X0,X1,X0}, bufout={X1,X0,X1,X0,out}
    const int relu[5] = {0, 1, 0, 1, 0};
    float* bufin[5]  = {X0, X1, X0, X1, X0};
    float* bufout[5] = {X1, X0, X1, X0, (float*)d_out};
    unsigned short* btP[5] = {Bt0, Bt0, Bt1, Bt0, Bt2};
    const float* attL[5]  = {attP[0], attP[0], attP[1], attP[0], attP[2]};
    const float* biasL[5] = {biasP[0], biasP[0], biasP[1], biasP[0], biasP[2]};

    int gA = (N + 3) / 4;
    int gB = (N + 63) / 64;
    for (int lyr = 0; lyr < 5; ++lyr) {
        if (lyr == 4)   // X1 (holding layer-3 input) is dead after l=3: reuse for set 2
            transposeB_kernel<<<128, 256, 0, stream>>>(basisP[2], rootP[2], Bt2);
        phaseA_kernel<<<gA, 256, 0, stream>>>(bufin[lyr], row_ptr, ssrc, stype, snid,
                                              attL[lyr], S, N);
        phaseB_kernel<<<gB, 256, 0, stream>>>(S, bufin[lyr], btP[lyr], biasL[lyr],
                                              bufout[lyr], N, relu[lyr]);
    }
}

// Round 15
// 1322.467 us; speedup vs baseline: 1.2146x; 1.2146x over previous
//
#include <hip/hip_runtime.h>

// RGCN on MI355X. CSR-by-dst built once, then per conv:
//   Phase A: S[n, b*100+d] = sum_{e: dst=n} att[type_e,b]*norm_e*invdeg_n * x[src_e,d]  (fp32)
//   Phase B: out = [S | x] @ [basis_flat ; root] + bias  via MFMA bf16 with 2-way
//            split (h+m, 3 products: hh+hm+mh). Dropped terms ~2^-14 rel -> ~1e-6
//            abs here (outputs ~0.01), 100x below the 1.22e-4 reassociation floor.
// R13: R12 measured VALU-cut without speedup -> conversion wasn't critical path;
// MFMA floor (41us) + LDS traffic + barrier lockstep at 1.6 blk/CU were. 2-way
// split halves MFMA+LDS and lifts occupancy to 5 blk/CU (LDS 30.7KB).
// (R15 = identical resubmit; R13 container failed, R14 GPU acquisition timeout.)

#define DIMD 100
#define NBASES 10
#define KTOT 1100          // 1000 (S@basis) + 100 (x@root)
#define KC 32              // k per chunk
#define NCHUNK 35          // 35*32 = 1120 >= 1100
#define KPAD 1120
#define BTPLANE (128 * KPAD)          // shorts per split level
#define BTSIZE (2 * BTPLANE)          // shorts per param set (573,440 B)

typedef __attribute__((ext_vector_type(8))) short short8;   // 8 bf16 = 4 VGPR
typedef __attribute__((ext_vector_type(4))) float floatx4;  // MFMA acc

static inline size_t align256(size_t x) { return (x + 255) & ~(size_t)255; }

__device__ inline unsigned short f2bf_rne(float f) {
    unsigned u = __float_as_uint(f);
    unsigned r = u + 0x7FFFu + ((u >> 16) & 1u);
    return (unsigned short)(r >> 16);
}
__device__ inline float bf2f(unsigned short h) {
    return __uint_as_float(((unsigned)h) << 16);
}

// ---------------- preprocessing kernels ----------------

__global__ __launch_bounds__(256) void hist_kernel(const int* __restrict__ dst,
                                                   int* __restrict__ counts, int E) {
    int e = blockIdx.x * 256 + threadIdx.x;
    if (e < E) atomicAdd(&counts[dst[e]], 1);
}

__global__ __launch_bounds__(1024) void scan_kernel(const int* __restrict__ counts,
                                                    int* __restrict__ row_ptr,
                                                    int* __restrict__ next_pos, int n) {
    __shared__ int part[1024];
    __shared__ int base_s[1024];
    int t = threadIdx.x;
    int chunk = (n + 1023) / 1024;
    int lo = t * chunk, hi = min(lo + chunk, n);
    int s = 0;
    for (int i = lo; i < hi; ++i) s += counts[i];
    part[t] = s;
    __syncthreads();
    if (t == 0) {
        int run = 0;
        for (int i = 0; i < 1024; ++i) { int v = part[i]; base_s[i] = run; run += v; }
        row_ptr[n] = run;   // == E
    }
    __syncthreads();
    int run = base_s[t];
    for (int i = lo; i < hi; ++i) {
        row_ptr[i] = run;
        next_pos[i] = run;
        run += counts[i];
    }
}

__global__ __launch_bounds__(256) void scatter_kernel(
        const int* __restrict__ src, const int* __restrict__ dst,
        const int* __restrict__ etype, const float* __restrict__ enorm,
        const int* __restrict__ counts, int* __restrict__ next_pos,
        int* __restrict__ ssrc, int* __restrict__ stype, float* __restrict__ snid, int E) {
    int e = blockIdx.x * 256 + threadIdx.x;
    if (e < E) {
        int d = dst[e];
        int pos = atomicAdd(&next_pos[d], 1);
        ssrc[pos] = src[e];
        stype[pos] = etype[e];
        float deg = (float)max(counts[d], 1);
        snid[pos] = enorm[e] / deg;   // fold mean into per-edge coef
    }
}

__global__ __launch_bounds__(256) void gather_kernel(const int* __restrict__ entity,
                                                     const float* __restrict__ emb,
                                                     float* __restrict__ x, int total) {
    int i = blockIdx.x * 256 + threadIdx.x;
    if (i < total) {
        int n = i / DIMD;
        int d = i - n * DIMD;
        x[i] = emb[(size_t)entity[n] * DIMD + d];
    }
}

// ---- B pre-transpose + 2-way bf16 split: Bt[lv][col][k], col<128, k<1120 ----
__global__ __launch_bounds__(256) void transposeB_kernel(
        const float* __restrict__ Bm,   // [1000][100] basis flat
        const float* __restrict__ root, // [100][100]
        unsigned short* __restrict__ Bt) {
    int col = blockIdx.x;               // 0..127
    for (int k = threadIdx.x; k < KPAD; k += 256) {
        float v = 0.f;
        if (col < DIMD && k < KTOT)
            v = (k < 1000) ? Bm[(size_t)k * DIMD + col]
                           : root[(size_t)(k - 1000) * DIMD + col];
        unsigned short h = f2bf_rne(v);  float r = v - bf2f(h);
        unsigned short m = f2bf_rne(r);
        size_t o = (size_t)col * KPAD + k;
        Bt[o] = h;
        Bt[BTPLANE + o] = m;
    }
}

// ---------------- Phase A: scatter into S (one wave per node) ----------------
// batch-4 edge pipeline (R12: measured neutral; phaseA is L3-gather-bound).

__global__ __launch_bounds__(256) void phaseA_kernel(
        const float* __restrict__ x, const int* __restrict__ row_ptr,
        const int* __restrict__ ssrc, const int* __restrict__ stype,
        const float* __restrict__ snid, const float* __restrict__ att,
        float* __restrict__ S, int N) {
    __shared__ float att_s[1000];   // [R=100][B=10]
    for (int i = threadIdx.x; i < 1000; i += 256) att_s[i] = att[i];
    __syncthreads();

    int wave = threadIdx.x >> 6;
    int l = threadIdx.x & 63;
    int n = blockIdx.x * 4 + wave;
    if (n >= N) return;

    int e0 = row_ptr[n], e1 = row_ptr[n + 1];
    float acc0[NBASES];
    float acc1[NBASES];
#pragma unroll
    for (int b = 0; b < NBASES; ++b) { acc0[b] = 0.f; acc1[b] = 0.f; }
    bool hi = (l < DIMD - 64);   // lanes 0..35 also own d = 64+l

    for (int e = e0; e < e1; e += 4) {
        float xa[4], xb[4], nv[4];
        int tt[4];
#pragma unroll
        for (int j = 0; j < 4; ++j) {          // 4 independent load chains
            if (e + j < e1) {
                int s = ssrc[e + j];
                tt[j] = stype[e + j];
                nv[j] = snid[e + j];
                const float* xr = x + (size_t)s * DIMD;
                xa[j] = xr[l];
                xb[j] = hi ? xr[64 + l] : 0.f;
            } else { tt[j] = 0; nv[j] = 0.f; xa[j] = 0.f; xb[j] = 0.f; }
        }
#pragma unroll
        for (int j = 0; j < 4; ++j) {
            const float* ar = att_s + tt[j] * NBASES;
#pragma unroll
            for (int b = 0; b < NBASES; ++b) {
                float c = ar[b] * nv[j];
                acc0[b] += c * xa[j];
                acc1[b] += c * xb[j];
            }
        }
    }
    float* Sr = S + (size_t)n * (NBASES * DIMD);
#pragma unroll
    for (int b = 0; b < NBASES; ++b) {
        Sr[b * DIMD + l] = acc0[b];
        if (hi) Sr[b * DIMD + 64 + l] = acc1[b];
    }
}

// ---------------- Phase B: MFMA 2-way-split bf16 GEMM ----------------
// Tile 64 rows x 128 cols, 4 waves (wave w = cols w*32..w*32+31), KC=32.
// A split per chunk via truncation (h=trunc, m=trunc(residual); residual
// after h+m <= 2^-14 rel). 3 MFMAs per (rf,cf): ah*bm + am*bh + ah*bh.
// LDS 30.7 KB -> 5 blocks/CU.

__global__ __launch_bounds__(256, 5) void phaseB_kernel(
        const float* __restrict__ S, const float* __restrict__ x,
        const unsigned short* __restrict__ Bt,   // [2][128][1120] bf16 pre-split
        const float* __restrict__ bias, float* __restrict__ out,
        int N, int do_relu) {
    __shared__ short Ah[64][40], Am[64][40];     //  5120 B each
    __shared__ short Bh[128][40], Bm_[128][40];  // 10240 B each

    int tid = threadIdx.x;
    int w = tid >> 6, l = tid & 63;
    int lr = l & 15, kg8 = (l >> 4) * 8;
    int n0 = blockIdx.x * 64;

    // staging coords: A: thread -> (row, k-group of 8); B: idx -> (col, k-quad)
    int arow = tid >> 2, akq = tid & 3;
    int gr = min(n0 + arow, N - 1);
    const float* Sr = S + (size_t)gr * 1000;
    const float* xr = x + (size_t)gr * DIMD;

    floatx4 acc[4][2];
#pragma unroll
    for (int rf = 0; rf < 4; ++rf)
#pragma unroll
        for (int cf = 0; cf < 2; ++cf) acc[rf][cf] = (floatx4)(0.f);

    for (int c = 0; c < NCHUNK; ++c) {
        int k0 = c * KC;
        __syncthreads();   // previous chunk's readers done

        // ---- issue A global loads ----
        int kgb = k0 + akq * 8;
        float4 va = make_float4(0.f, 0.f, 0.f, 0.f), vb = va;
        if (kgb < 1000)      va = *(const float4*)(Sr + kgb);
        else if (kgb < KTOT) va = *(const float4*)(xr + (kgb - 1000));
        int kgb2 = kgb + 4;
        if (kgb2 < 1000)      vb = *(const float4*)(Sr + kgb2);
        else if (kgb2 < KTOT) vb = *(const float4*)(xr + (kgb2 - 1000));

        // ---- issue B global loads (pre-split bf16, 4x b128) ----
        short8 vB[4];
#pragma unroll
        for (int lv = 0; lv < 2; ++lv) {
            const unsigned short* plane = Bt + (size_t)lv * BTPLANE;
#pragma unroll
            for (int i = 0; i < 2; ++i) {
                int idx = tid + i * 256;            // 0..511
                int col = idx >> 2, kq = idx & 3;
                vB[lv * 2 + i] = *(const short8*)(plane + (size_t)col * KPAD + k0 + kq * 8);
            }
        }

        // ---- convert A: 2-way truncation split (waits only on A loads) ----
        {
            float v[8] = {va.x, va.y, va.z, va.w, vb.x, vb.y, vb.z, vb.w};
            unsigned hU[4], mU[4];
#pragma unroll
            for (int i = 0; i < 4; ++i) {
                float a = v[2 * i], b = v[2 * i + 1];
                unsigned ua = __float_as_uint(a), ub = __float_as_uint(b);
                float ha = __uint_as_float(ua & 0xFFFF0000u);
                float hb = __uint_as_float(ub & 0xFFFF0000u);
                hU[i] = (ua >> 16) | (ub & 0xFFFF0000u);
                float ra = a - ha, rb = b - hb;          // exact residuals
                unsigned ura = __float_as_uint(ra), urb = __float_as_uint(rb);
                mU[i] = (ura >> 16) | (urb & 0xFFFF0000u);
            }
            *(uint4*)&Ah[arow][akq * 8] = make_uint4(hU[0], hU[1], hU[2], hU[3]);
            *(uint4*)&Am[arow][akq * 8] = make_uint4(mU[0], mU[1], mU[2], mU[3]);
        }
        // ---- write B planes ----
#pragma unroll
        for (int lv = 0; lv < 2; ++lv) {
#pragma unroll
            for (int i = 0; i < 2; ++i) {
                int idx = tid + i * 256;
                int col = idx >> 2, kq = idx & 3;
                short* dstL = (lv == 0) ? &Bh[col][kq * 8] : &Bm_[col][kq * 8];
                *(short8*)dstL = vB[lv * 2 + i];
            }
        }
        __syncthreads();

        // ---- B frags for this wave's 2 col-frags ----
        short8 bh[2], bm[2];
#pragma unroll
        for (int cf = 0; cf < 2; ++cf) {
            int bc = w * 32 + cf * 16 + lr;
            bh[cf] = *(const short8*)&Bh[bc][kg8];
            bm[cf] = *(const short8*)&Bm_[bc][kg8];
        }
        // ---- 4 row-frags x 2 col-frags x 3 products ----
#pragma unroll
        for (int rf = 0; rf < 4; ++rf) {
            int ar = rf * 16 + lr;
            short8 ah = *(const short8*)&Ah[ar][kg8];
            short8 am = *(const short8*)&Am[ar][kg8];
#pragma unroll
            for (int cf = 0; cf < 2; ++cf) {
                floatx4 a = acc[rf][cf];
                a = __builtin_amdgcn_mfma_f32_16x16x32_bf16(ah, bm[cf], a, 0, 0, 0);
                a = __builtin_amdgcn_mfma_f32_16x16x32_bf16(am, bh[cf], a, 0, 0, 0);
                a = __builtin_amdgcn_mfma_f32_16x16x32_bf16(ah, bh[cf], a, 0, 0, 0);
                acc[rf][cf] = a;
            }
        }
    }

    // ---- epilogue: C/D layout col=lane&15, row=(lane>>4)*4+j (m89-verified) ----
#pragma unroll
    for (int rf = 0; rf < 4; ++rf) {
#pragma unroll
        for (int cf = 0; cf < 2; ++cf) {
            int cidx = w * 32 + cf * 16 + lr;
            if (cidx < DIMD) {
                float bs = bias[cidx];
#pragma unroll
                for (int j = 0; j < 4; ++j) {
                    int r = n0 + rf * 16 + (l >> 4) * 4 + j;
                    if (r < N) {
                        float v = acc[rf][cf][j] + bs;
                        if (do_relu) v = fmaxf(v, 0.f);
                        out[(size_t)r * DIMD + cidx] = v;
                    }
                }
            }
        }
    }
}

// ---------------- driver ----------------

extern "C" void kernel_launch(void* const* d_in, const int* in_sizes, int n_in,
                              void* d_out, int out_size, void* d_ws, size_t ws_size,
                              hipStream_t stream) {
    const int* entity = (const int*)d_in[0];
    const int* edge_index = (const int*)d_in[1];
    const int* edge_type = (const int*)d_in[2];
    const float* edge_norm = (const float*)d_in[3];
    const float* emb = (const float*)d_in[4];
    const float* basisP[3] = {(const float*)d_in[5], (const float*)d_in[9], (const float*)d_in[13]};
    const float* attP[3]   = {(const float*)d_in[6], (const float*)d_in[10], (const float*)d_in[14]};
    const float* rootP[3]  = {(const float*)d_in[7], (const float*)d_in[11], (const float*)d_in[15]};
    const float* biasP[3]  = {(const float*)d_in[8], (const float*)d_in[12], (const float*)d_in[16]};

    const int N = in_sizes[0];
    const int E = in_sizes[1] / 2;
    const int* src = edge_index;
    const int* dst = edge_index + E;

    // workspace layout: R4's proven 250.2 MB footprint (unchanged)
    char* w = (char*)d_ws;
    float* S = (float*)w;            w += align256((size_t)N * NBASES * DIMD * 4);
    float* X0 = (float*)w;           w += align256((size_t)N * DIMD * 4);
    float* X1 = (float*)w;           w += align256((size_t)N * DIMD * 4);
    int* counts = (int*)w;           w += align256((size_t)N * 4);
    int* row_ptr = (int*)w;          w += align256((size_t)(N + 1) * 4);
    int* next_pos = (int*)w;         w += align256((size_t)N * 4);
    int* ssrc = (int*)w;             w += align256((size_t)E * 4);
    int* stype = (int*)w;            w += align256((size_t)E * 4);
    float* snid = (float*)w;         w += align256((size_t)E * 4);

    // Bt scratch: sets 0/1 live in d_out (scratch until l=4 writes it);
    // set 2 lives in X1 (dead after l=3 consumes it).
    unsigned short* Bt0 = (unsigned short*)d_out;
    unsigned short* Bt1 = Bt0 + BTSIZE;
    unsigned short* Bt2 = (unsigned short*)X1;

    // ---- build CSR by dst (shared by all 5 convs) ----
    hipMemsetAsync(counts, 0, (size_t)N * 4, stream);
    int gE = (E + 255) / 256;
    hist_kernel<<<gE, 256, 0, stream>>>(dst, counts, E);
    scan_kernel<<<1, 1024, 0, stream>>>(counts, row_ptr, next_pos, N);
    scatter_kernel<<<gE, 256, 0, stream>>>(src, dst, edge_type, edge_norm, counts,
                                           next_pos, ssrc, stype, snid, E);
    // ---- x0 = emb[entity] ----
    int totalX = N * DIMD;
    gather_kernel<<<(totalX + 255) / 256, 256, 0, stream>>>(entity, emb, X0, totalX);

    // ---- pre-split B for param sets 0 and 1 ----
    transposeB_kernel<<<128, 256, 0, stream>>>(basisP[0], rootP[0], Bt0);
    transposeB_kernel<<<128, 256, 0, stream>>>(basisP[1], rootP[1], Bt1);

    // ---- 5 conv layers: rotation bufin={X0,X1,X0,X1,X0}, bufout={X1,X0,X1,X0,out}
    const int relu[5] = {0, 1, 0, 1, 0};
    float* bufin[5]  = {X0, X1, X0, X1, X0};
    float* bufout[5] = {X1, X0, X1, X0, (float*)d_out};
    unsigned short* btP[5] = {Bt0, Bt0, Bt1, Bt0, Bt2};
    const float* attL[5]  = {attP[0], attP[0], attP[1], attP[0], attP[2]};
    const float* biasL[5] = {biasP[0], biasP[0], biasP[1], biasP[0], biasP[2]};

    int gA = (N + 3) / 4;
    int gB = (N + 63) / 64;
    for (int lyr = 0; lyr < 5; ++lyr) {
        if (lyr == 4)   // X1 (holding layer-3 input) is dead after l=3: reuse for set 2
            transposeB_kernel<<<128, 256, 0, stream>>>(basisP[2], rootP[2], Bt2);
        phaseA_kernel<<<gA, 256, 0, stream>>>(bufin[lyr], row_ptr, ssrc, stype, snid,
                                              attL[lyr], S, N);
        phaseB_kernel<<<gB, 256, 0, stream>>>(S, bufin[lyr], btP[lyr], biasL[lyr],
                                              bufout[lyr], N, relu[lyr]);
    }
}